// Round 2
// baseline (466.374 us; speedup 1.0000x reference)
//
#include <hip/hip_runtime.h>
#include <cmath>

#define HDIM 2048
#define NEXP 16
#define IDIM 512
#define ISDIM 2048
#define NTOK 2048
#define MAXT 48                 // 128-row expert tiles: 4096/128 + 16
#define ROWSCAP (MAXT * 128)    // 6144

#define GU_EXP (MAXT * 4)                    // 192 (IDIM/128 = 4 n-tiles)
#define GU_SH ((NTOK / 128) * (ISDIM / 128)) // 256
#define DN_SH ((NTOK / 128) * (HDIM / 256))  // 128
#define DN_EXP (MAXT * 8)                    // 384 (HDIM/256 = 8 n-tiles)

typedef short bf16x8 __attribute__((ext_vector_type(8)));
typedef float f32x4 __attribute__((ext_vector_type(4)));
typedef unsigned short us;
typedef __attribute__((address_space(1))) const unsigned int* as1p;
typedef __attribute__((address_space(3))) unsigned int* as3p;

__device__ __forceinline__ us f2bf(float f) {
  unsigned int u = __builtin_bit_cast(unsigned int, f);
  u += 0x7FFFu + ((u >> 16) & 1u);
  return (us)(u >> 16);
}
__device__ __forceinline__ float bf2f(us v) {
  return __builtin_bit_cast(float, (unsigned)v << 16);
}

// async 16B/lane global->LDS; global vaddr per-lane, LDS base wave-uniform
__device__ __forceinline__ void glds16(const void* g, void* l) {
  __builtin_amdgcn_global_load_lds((as1p)(unsigned long long)g,
                                   (as3p)(unsigned int)(unsigned long long)l, 16, 0, 0);
}

__device__ __forceinline__ void load8(const float* __restrict__ src,
                                      float4& a, float4& b) {
  const float4* p = (const float4*)src;
  a = p[0];
  b = p[1];
}

// convert 8 fp32 (round-half-up, same as prior passing kernels) -> 16B LDS write
__device__ __forceinline__ void cvt8_store(float4 a, float4 b, us* __restrict__ dst) {
  unsigned u0 = __builtin_bit_cast(unsigned, a.x) + 0x8000u;
  unsigned u1 = __builtin_bit_cast(unsigned, a.y) + 0x8000u;
  unsigned u2 = __builtin_bit_cast(unsigned, a.z) + 0x8000u;
  unsigned u3 = __builtin_bit_cast(unsigned, a.w) + 0x8000u;
  unsigned u4 = __builtin_bit_cast(unsigned, b.x) + 0x8000u;
  unsigned u5 = __builtin_bit_cast(unsigned, b.y) + 0x8000u;
  unsigned u6 = __builtin_bit_cast(unsigned, b.z) + 0x8000u;
  unsigned u7 = __builtin_bit_cast(unsigned, b.w) + 0x8000u;
  int4 v;
  v.x = __builtin_amdgcn_perm(u1, u0, 0x07060302);
  v.y = __builtin_amdgcn_perm(u3, u2, 0x07060302);
  v.z = __builtin_amdgcn_perm(u5, u4, 0x07060302);
  v.w = __builtin_amdgcn_perm(u7, u6, 0x07060302);
  *(int4*)dst = v;
}

// ------- kernel 1: router (wave per token) + x->bf16 conversion fused -----
__global__ __launch_bounds__(256) void k_router(const float* __restrict__ x,
                                                const float* __restrict__ gate_w,
                                                const float* __restrict__ sgw,
                                                us* __restrict__ xb,
                                                int* __restrict__ sel,
                                                float* __restrict__ wnorm,
                                                float* __restrict__ sig,
                                                int* __restrict__ counts) {
  __shared__ float lg[4][17];
  int tid = threadIdx.x, wid = tid >> 6, lane = tid & 63;
  int t = blockIdx.x * 4 + wid;
  const float4* xrow = reinterpret_cast<const float4*>(x + (size_t)t * HDIM);
  float4 xv[8];
#pragma unroll
  for (int s = 0; s < 8; s++) xv[s] = xrow[s * 64 + lane];
  ushort4* xbrow = reinterpret_cast<ushort4*>(xb + (size_t)t * HDIM);
#pragma unroll
  for (int s = 0; s < 8; s++) {
    ushort4 o;
    o.x = f2bf(xv[s].x); o.y = f2bf(xv[s].y); o.z = f2bf(xv[s].z); o.w = f2bf(xv[s].w);
    xbrow[s * 64 + lane] = o;
  }
#pragma unroll 1
  for (int e = 0; e < 17; e++) {
    const float4* gr =
        reinterpret_cast<const float4*>(e < 16 ? gate_w + (size_t)e * HDIM : sgw);
    float acc = 0.f;
#pragma unroll
    for (int s = 0; s < 8; s++) {
      float4 g = gr[s * 64 + lane];
      acc += xv[s].x * g.x + xv[s].y * g.y + xv[s].z * g.z + xv[s].w * g.w;
    }
#pragma unroll
    for (int off = 32; off; off >>= 1) acc += __shfl_xor(acc, off, 64);
    if (lane == 0) lg[wid][e] = acc;
  }
  if (lane == 0) {
    float* L = lg[wid];
    int i1 = 0; float v1 = L[0];
    for (int i = 1; i < NEXP; i++) if (L[i] > v1) { v1 = L[i]; i1 = i; }
    int i2 = (i1 == 0) ? 1 : 0; float v2 = L[i2];
    for (int i = 0; i < NEXP; i++)
      if (i != i1 && i != i2 && L[i] > v2) { v2 = L[i]; i2 = i; }
    float wa = 1.f / (1.f + expf(v2 - v1));  // renorm top-2 softmax
    sel[2 * t] = i1; sel[2 * t + 1] = i2;
    wnorm[2 * t] = wa; wnorm[2 * t + 1] = 1.f - wa;
    sig[t] = 1.f / (1.f + expf(-L[16]));
    atomicAdd(&counts[i1], 1);
    atomicAdd(&counts[i2], 1);
  }
}

// ------- kernel 2: scan + scatter (128-aligned offsets) -------------------
__global__ __launch_bounds__(256) void k_scan_scatter(const int* __restrict__ counts,
                                                      const int* __restrict__ sel,
                                                      const float* __restrict__ wnorm,
                                                      int* __restrict__ tile_expert,
                                                      int* __restrict__ row_token,
                                                      int* __restrict__ rowk,
                                                      float* __restrict__ rw) {
  __shared__ int offs_s[NEXP];
  __shared__ int fill_s[NEXP];
  int tid = threadIdx.x;
  for (int r = tid; r < ROWSCAP; r += 256) row_token[r] = -1;
  if (tid < NEXP) fill_s[tid] = 0;
  if (tid == 0) {
    int acc = 0;
    for (int e = 0; e < NEXP; e++) {
      offs_s[e] = acc;
      int nt = (counts[e] + 127) >> 7;
      for (int i = 0; i < nt; i++) tile_expert[(acc >> 7) + i] = e;
      acc += nt << 7;
    }
    for (int m = acc >> 7; m < MAXT; m++) tile_expert[m] = -1;
  }
  __syncthreads();
  for (int t = tid; t < NTOK; t += 256) {
    for (int k = 0; k < 2; k++) {
      int e = sel[2 * t + k];
      int pos = atomicAdd(&fill_s[e], 1);
      int row = offs_s[e] + pos;
      row_token[row] = t;
      rowk[row] = k;
      rw[row] = wnorm[2 * t + k];
    }
  }
}

// ------- kernel 3: gate/up GEMM, 128x128 tiles, fp32 B, T14 pipeline ------
// waves 0-3: G matrix (2x2 of 64x64), waves 4-7: U. Epilogue joins via LDS.
// A: glds16 double-buffered. B: fp32 global->reg issued 1 step ahead,
// convert+ds_write at top of next step. BAR2 is a raw s_barrier (no vm drain)
// so in-flight k+1 loads cross it.
__global__ __launch_bounds__(512) void k_gu(
    const us* __restrict__ xb, const float* __restrict__ w1,
    const float* __restrict__ w3, const float* __restrict__ wsg,
    const float* __restrict__ wsu, const int* __restrict__ tile_expert,
    const int* __restrict__ row_token, us* __restrict__ hmid,
    us* __restrict__ hs) {
  __shared__ us As[2][128 * 64];   // 32KB double-buffered A
  __shared__ us Bs[2][128 * 64];   // 32KB (G,U); reused as 128x128 U-buf in epilogue
  __shared__ int toks_s[128];
  int bid = blockIdx.x, tid = threadIdx.x;
  int w = tid >> 6, lane = tid & 63;
  const float *bG, *bU;
  us* outp;
  int mt, n0, ostride;
  if (bid < GU_EXP) {
    mt = bid >> 2; int nt = bid & 3;
    int e = tile_expert[mt];
    if (e < 0) return;
    if (tid < 128) {
      int tk = row_token[mt * 128 + tid];
      toks_s[tid] = tk < 0 ? 0 : tk;
    }
    bG = w1 + ((size_t)e * IDIM + nt * 128) * HDIM;
    bU = w3 + ((size_t)e * IDIM + nt * 128) * HDIM;
    outp = hmid; ostride = IDIM; n0 = nt * 128;
  } else {
    int sb = bid - GU_EXP;
    mt = sb >> 4; int nt = sb & 15;
    if (tid < 128) toks_s[tid] = mt * 128 + tid;
    bG = wsg + (size_t)(nt * 128) * HDIM;
    bU = wsu + (size_t)(nt * 128) * HDIM;
    outp = hs; ostride = ISDIM; n0 = nt * 128;
  }
  __syncthreads();
  int lr = lane >> 3, lc = lane & 7;
  int swz = (lc ^ lr) * 8;
  const us* aSrc0 = xb + (size_t)toks_s[w * 16 + lr] * HDIM + swz;
  const us* aSrc1 = xb + (size_t)toks_s[w * 16 + 8 + lr] * HDIM + swz;
  // B staging slots: 2 per matrix per thread (slot = row*8+pc, 128 rows)
  int r0 = tid >> 3, p0 = tid & 7, g0 = p0 ^ (r0 & 7);
  int r1 = r0 + 64, g1 = p0 ^ (r1 & 7);
  size_t bo0 = (size_t)r0 * HDIM + g0 * 8;
  size_t bo1 = (size_t)r1 * HDIM + g1 * 8;
  int mat = w >> 2, sub = w & 3, wm = sub >> 1, wn = sub & 1;
  int quad = lane >> 4, l16 = lane & 15, sw = l16 & 7;
  us* aCur = As[0];
  us* aNxt = As[1];
  // prologue: A glds + B reg-loads for k=0
  glds16(aSrc0, aCur + w * 1024);
  glds16(aSrc1, aCur + w * 1024 + 512);
  float4 g0a, g0b, g1a, g1b, u0a, u0b, u1a, u1b;
  load8(bG + bo0, g0a, g0b);
  load8(bG + bo1, g1a, g1b);
  load8(bU + bo0, u0a, u0b);
  load8(bU + bo1, u1a, u1b);
  f32x4 acc[4][4] = {};
  for (int k0 = 0; k0 < HDIM; k0 += 64) {
    // convert current B regs -> LDS
    cvt8_store(g0a, g0b, &Bs[0][(r0 * 8 + p0) * 8]);
    cvt8_store(g1a, g1b, &Bs[0][(r1 * 8 + p0) * 8]);
    cvt8_store(u0a, u0b, &Bs[1][(r0 * 8 + p0) * 8]);
    cvt8_store(u1a, u1b, &Bs[1][(r1 * 8 + p0) * 8]);
    __syncthreads();  // BAR1: drains aCur glds (1 iter old) + B ds_writes
    if (k0 + 64 < HDIM) {  // issue next tile's loads; they fly during MFMA
      glds16(aSrc0 + k0 + 64, aNxt + w * 1024);
      glds16(aSrc1 + k0 + 64, aNxt + w * 1024 + 512);
      load8(bG + bo0 + k0 + 64, g0a, g0b);
      load8(bG + bo1 + k0 + 64, g1a, g1b);
      load8(bU + bo0 + k0 + 64, u0a, u0b);
      load8(bU + bo1 + k0 + 64, u1a, u1b);
    }
#pragma unroll
    for (int ks = 0; ks < 2; ks++) {
      int cb = (ks * 4 + quad) ^ sw;
      bf16x8 af[4], bf[4];
#pragma unroll
      for (int ms = 0; ms < 4; ms++)
        af[ms] = *(const bf16x8*)&aCur[((wm * 64 + ms * 16 + l16) * 8 + cb) * 8];
#pragma unroll
      for (int ns = 0; ns < 4; ns++)
        bf[ns] = *(const bf16x8*)&Bs[mat][((wn * 64 + ns * 16 + l16) * 8 + cb) * 8];
#pragma unroll
      for (int ms = 0; ms < 4; ms++)
#pragma unroll
        for (int ns = 0; ns < 4; ns++)
          acc[ms][ns] = __builtin_amdgcn_mfma_f32_16x16x32_bf16(af[ms], bf[ns], acc[ms][ns], 0, 0, 0);
    }
    // BAR2: raw barrier, no vmcnt drain — only LDS read-before-overwrite
    // ordering needed (frag ds_reads already lgkm-waited before MFMA use)
    __builtin_amdgcn_sched_barrier(0);
    __builtin_amdgcn_s_barrier();
    __builtin_amdgcn_sched_barrier(0);
    us* t = aCur; aCur = aNxt; aNxt = t;
  }
  // epilogue: U waves park u (bf16) in LDS; G waves do silu(g)*u -> store
  us* ub = (us*)Bs;
  if (mat == 1) {
#pragma unroll
    for (int ms = 0; ms < 4; ms++)
#pragma unroll
      for (int ns = 0; ns < 4; ns++)
#pragma unroll
        for (int r = 0; r < 4; r++) {
          int row = wm * 64 + ms * 16 + quad * 4 + r;
          int col = wn * 64 + ns * 16 + l16;
          ub[row * 128 + col] = f2bf(acc[ms][ns][r]);
        }
  }
  __syncthreads();
  if (mat == 0) {
#pragma unroll
    for (int ms = 0; ms < 4; ms++)
#pragma unroll
      for (int ns = 0; ns < 4; ns++)
#pragma unroll
        for (int r = 0; r < 4; r++) {
          int row = wm * 64 + ms * 16 + quad * 4 + r;
          int col = wn * 64 + ns * 16 + l16;
          float g = acc[ms][ns][r];
          float u = bf2f(ub[row * 128 + col]);
          float hv = (g / (1.f + __expf(-g))) * u;
          outp[(size_t)(mt * 128 + row) * ostride + n0 + col] = f2bf(hv);
        }
  }
}

// ------- kernel 4: down GEMMs 128x256, fp32 B, T14 pipeline ---------------
__global__ __launch_bounds__(512) void k_down(
    const us* __restrict__ hmid, const us* __restrict__ hs,
    const float* __restrict__ w2, const float* __restrict__ wsd,
    const int* __restrict__ tile_expert, const int* __restrict__ row_token,
    const int* __restrict__ rowk, const float* __restrict__ rw,
    const float* __restrict__ sig, us* __restrict__ slab) {
  __shared__ us As[2][128 * 64];  // 32KB double-buffered A
  __shared__ us Bs[256 * 64];     // 32KB
  __shared__ int idx_s[128];
  __shared__ float wgt_s[128];
  int bid = blockIdx.x, tid = threadIdx.x;
  int w = tid >> 6, lane = tid & 63;
  const us* aBase;
  const float* bBase;
  int K, mt, n0;
  if (bid < DN_SH) {  // shared expert first (K=2048, longest)
    mt = bid >> 3; int nt = bid & 7;
    aBase = hs + (size_t)mt * 128 * ISDIM; K = ISDIM;
    bBase = wsd + (size_t)(nt * 256) * ISDIM;
    n0 = nt * 256;
    if (tid < 128) {
      int t = mt * 128 + tid;
      idx_s[tid] = 2 * NTOK * HDIM + t * HDIM;
      wgt_s[tid] = sig[t];
    }
  } else {
    int sb = bid - DN_SH;
    mt = sb >> 3; int nt = sb & 7;
    int e = tile_expert[mt];
    if (e < 0) return;
    aBase = hmid + (size_t)mt * 128 * IDIM; K = IDIM;
    bBase = w2 + ((size_t)e * HDIM + nt * 256) * IDIM;
    n0 = nt * 256;
    if (tid < 128) {
      int tk = row_token[mt * 128 + tid];
      if (tk < 0) { idx_s[tid] = -1; wgt_s[tid] = 0.f; }
      else {
        idx_s[tid] = (rowk[mt * 128 + tid] * NTOK + tk) * HDIM;
        wgt_s[tid] = rw[mt * 128 + tid];
      }
    }
  }
  __syncthreads();
  int lr = lane >> 3, lc = lane & 7;
  int swz = (lc ^ lr) * 8;
  const us* aSrc0 = aBase + (size_t)(w * 16 + lr) * K + swz;
  const us* aSrc1 = aBase + (size_t)(w * 16 + 8 + lr) * K + swz;
  // B staging: 4 slots/thread over 256 rows x 8 chunks; row&7 == r0&7 for all
  int r0 = tid >> 3, p0 = tid & 7, gc = p0 ^ (r0 & 7);
  const float* bS = bBase + (size_t)r0 * K + gc * 8;
  int wmn = w >> 2, wn = w & 3;  // waves 2(m) x 4(n)
  int quad = lane >> 4, l16 = lane & 15, sw = l16 & 7;
  us* aCur = As[0];
  us* aNxt = As[1];
  glds16(aSrc0, aCur + w * 1024);
  glds16(aSrc1, aCur + w * 1024 + 512);
  float4 b0a, b0b, b1a, b1b, b2a, b2b, b3a, b3b;
  load8(bS + (size_t)0 * 64 * K, b0a, b0b);
  load8(bS + (size_t)1 * 64 * K, b1a, b1b);
  load8(bS + (size_t)2 * 64 * K, b2a, b2b);
  load8(bS + (size_t)3 * 64 * K, b3a, b3b);
  f32x4 acc[4][4] = {};
  for (int k0 = 0; k0 < K; k0 += 64) {
    cvt8_store(b0a, b0b, &Bs[((r0 + 0) * 8 + p0) * 8]);
    cvt8_store(b1a, b1b, &Bs[((r0 + 64) * 8 + p0) * 8]);
    cvt8_store(b2a, b2b, &Bs[((r0 + 128) * 8 + p0) * 8]);
    cvt8_store(b3a, b3b, &Bs[((r0 + 192) * 8 + p0) * 8]);
    __syncthreads();  // BAR1
    if (k0 + 64 < K) {
      glds16(aSrc0 + k0 + 64, aNxt + w * 1024);
      glds16(aSrc1 + k0 + 64, aNxt + w * 1024 + 512);
      load8(bS + (size_t)0 * 64 * K + k0 + 64, b0a, b0b);
      load8(bS + (size_t)1 * 64 * K + k0 + 64, b1a, b1b);
      load8(bS + (size_t)2 * 64 * K + k0 + 64, b2a, b2b);
      load8(bS + (size_t)3 * 64 * K + k0 + 64, b3a, b3b);
    }
#pragma unroll
    for (int ks = 0; ks < 2; ks++) {
      int cb = (ks * 4 + quad) ^ sw;
      bf16x8 af[4], bf[4];
#pragma unroll
      for (int ms = 0; ms < 4; ms++)
        af[ms] = *(const bf16x8*)&aCur[((wmn * 64 + ms * 16 + l16) * 8 + cb) * 8];
#pragma unroll
      for (int ns = 0; ns < 4; ns++)
        bf[ns] = *(const bf16x8*)&Bs[((wn * 64 + ns * 16 + l16) * 8 + cb) * 8];
#pragma unroll
      for (int ms = 0; ms < 4; ms++)
#pragma unroll
        for (int ns = 0; ns < 4; ns++)
          acc[ms][ns] = __builtin_amdgcn_mfma_f32_16x16x32_bf16(af[ms], bf[ns], acc[ms][ns], 0, 0, 0);
    }
    __builtin_amdgcn_sched_barrier(0);
    __builtin_amdgcn_s_barrier();
    __builtin_amdgcn_sched_barrier(0);
    us* t = aCur; aCur = aNxt; aNxt = t;
  }
#pragma unroll
  for (int ms = 0; ms < 4; ms++)
#pragma unroll
    for (int r = 0; r < 4; r++) {
      int rr = wmn * 64 + ms * 16 + quad * 4 + r;
      int ix = idx_s[rr];
      if (ix >= 0) {
        float wgt = wgt_s[rr];
        us* orow = slab + (size_t)ix + n0 + wn * 64;
#pragma unroll
        for (int ns = 0; ns < 4; ns++)
          orow[ns * 16 + l16] = f2bf(wgt * acc[ms][ns][r]);
      }
    }
}

// ------- kernel 5: out = slot0 + slot1 + sig*shared (streaming) -----------
__global__ __launch_bounds__(256) void k_combine(const us* __restrict__ slab,
                                                 float* __restrict__ out) {
  size_t i = ((size_t)blockIdx.x * 256 + threadIdx.x) * 8;
  bf16x8 a = *(const bf16x8*)(slab + i);
  bf16x8 b = *(const bf16x8*)(slab + (size_t)NTOK * HDIM + i);
  bf16x8 c = *(const bf16x8*)(slab + 2 * (size_t)NTOK * HDIM + i);
  float4 o[2];
#pragma unroll
  for (int j = 0; j < 8; j++)
    ((float*)o)[j] = bf2f((us)a[j]) + bf2f((us)b[j]) + bf2f((us)c[j]);
  *(float4*)(out + i) = o[0];
  *(float4*)(out + i + 4) = o[1];
}

extern "C" void kernel_launch(void* const* d_in, const int* in_sizes, int n_in,
                              void* d_out, int out_size, void* d_ws, size_t ws_size,
                              hipStream_t stream) {
  const float* x = (const float*)d_in[0];
  const float* gate_w = (const float*)d_in[1];
  const float* w1 = (const float*)d_in[2];
  const float* w2 = (const float*)d_in[3];
  const float* w3 = (const float*)d_in[4];
  const float* wsg = (const float*)d_in[5];
  const float* wsu = (const float*)d_in[6];
  const float* wsd = (const float*)d_in[7];
  const float* sgw = (const float*)d_in[8];
  float* out = (float*)d_out;

  // workspace carve (16B aligned)
  us* xb = (us*)d_ws;                               // NTOK*HDIM
  us* hs = xb + (size_t)NTOK * HDIM;                // NTOK*ISDIM
  us* hmid = hs + (size_t)NTOK * ISDIM;             // ROWSCAP*IDIM
  us* slab = hmid + (size_t)ROWSCAP * IDIM;         // 3*NTOK*HDIM
  float* rw = (float*)(slab + (size_t)3 * NTOK * HDIM);  // ROWSCAP
  float* wnorm = rw + ROWSCAP;                      // 4096
  float* sig = wnorm + 2 * NTOK;                    // 2048
  int* sel = (int*)(sig + NTOK);                    // 4096
  int* row_token = sel + 2 * NTOK;                  // ROWSCAP
  int* rowk = row_token + ROWSCAP;                  // ROWSCAP
  int* counts = rowk + ROWSCAP;                     // 16
  int* tile_expert = counts + NEXP;                 // MAXT

  hipMemsetAsync(counts, 0, NEXP * sizeof(int), stream);
  k_router<<<dim3(NTOK / 4), dim3(256), 0, stream>>>(x, gate_w, sgw, xb, sel, wnorm,
                                                     sig, counts);
  k_scan_scatter<<<dim3(1), dim3(256), 0, stream>>>(counts, sel, wnorm, tile_expert,
                                                    row_token, rowk, rw);
  k_gu<<<dim3(GU_EXP + GU_SH), dim3(512), 0, stream>>>(
      xb, w1, w3, wsg, wsu, tile_expert, row_token, hmid, hs);
  k_down<<<dim3(DN_SH + DN_EXP), dim3(512), 0, stream>>>(
      hmid, hs, w2, wsd, tile_expert, row_token, rowk, rw, sig, slab);
  k_combine<<<dim3(NTOK * HDIM / 2048), dim3(256), 0, stream>>>(slab, out);
}

// Round 3
// 463.324 us; speedup vs baseline: 1.0066x; 1.0066x over previous
//
#include <hip/hip_runtime.h>
#include <cmath>

#define HDIM 2048
#define NEXP 16
#define IDIM 512
#define ISDIM 2048
#define NTOK 2048
#define MAXT 48                 // 128-row expert tiles: 4096/128 + 16
#define ROWSCAP (MAXT * 128)    // 6144

#define GU_EXP (MAXT * 4)                    // 192 (IDIM/128 = 4 n-tiles)
#define GU_SH ((NTOK / 128) * (ISDIM / 128)) // 256
#define DN_SH ((NTOK / 128) * (HDIM / 256))  // 128
#define DN_EXP (MAXT * 8)                    // 384 (HDIM/256 = 8 n-tiles)

typedef short bf16x8 __attribute__((ext_vector_type(8)));
typedef float f32x4 __attribute__((ext_vector_type(4)));
typedef unsigned int u32x4 __attribute__((ext_vector_type(4)));
typedef unsigned short us;
typedef __attribute__((address_space(1))) const unsigned int* as1p;
typedef __attribute__((address_space(3))) unsigned int* as3p;

__device__ __forceinline__ us f2bf(float f) {
  unsigned int u = __builtin_bit_cast(unsigned int, f);
  u += 0x7FFFu + ((u >> 16) & 1u);
  return (us)(u >> 16);
}
__device__ __forceinline__ float bf2f(us v) {
  return __builtin_bit_cast(float, (unsigned)v << 16);
}

// async 16B/lane global->LDS; global vaddr per-lane, LDS base wave-uniform
__device__ __forceinline__ void glds16(const void* g, void* l) {
  __builtin_amdgcn_global_load_lds((as1p)(unsigned long long)g,
                                   (as3p)(unsigned int)(unsigned long long)l, 16, 0, 0);
}

// load 8 fp32 NON-TEMPORAL (single-use stream; don't evict L3), round-half-up
// to bf16 (same arithmetic as all prior passing rounds), 16B cacheable store.
__device__ __forceinline__ void cvt8_nt(const unsigned* __restrict__ src,
                                        us* __restrict__ dst) {
  u32x4 a = __builtin_nontemporal_load((const u32x4*)src);
  u32x4 b = __builtin_nontemporal_load((const u32x4*)(src + 4));
  unsigned u0 = a.x + 0x8000u;
  unsigned u1 = a.y + 0x8000u;
  unsigned u2 = a.z + 0x8000u;
  unsigned u3 = a.w + 0x8000u;
  unsigned u4 = b.x + 0x8000u;
  unsigned u5 = b.y + 0x8000u;
  unsigned u6 = b.z + 0x8000u;
  unsigned u7 = b.w + 0x8000u;
  int4 v;
  v.x = __builtin_amdgcn_perm(u1, u0, 0x07060302);
  v.y = __builtin_amdgcn_perm(u3, u2, 0x07060302);
  v.z = __builtin_amdgcn_perm(u5, u4, 0x07060302);
  v.w = __builtin_amdgcn_perm(u7, u6, 0x07060302);
  *(int4*)dst = v;
}

// ------- kernel 0: one-shot weight fp32->bf16 convert (streaming) ---------
__global__ __launch_bounds__(256) void k_cvt(
    const float* __restrict__ w1, const float* __restrict__ w2,
    const float* __restrict__ w3, const float* __restrict__ wsg,
    const float* __restrict__ wsu, const float* __restrict__ wsd,
    us* __restrict__ w1b, us* __restrict__ w2b, us* __restrict__ w3b,
    us* __restrict__ wsgb, us* __restrict__ wsub, us* __restrict__ wsdb) {
  int b = blockIdx.x;
  const float* src;
  us* dst;
  if (b < 8192) { src = w1; dst = w1b; }
  else if (b < 16384) { src = w2; dst = w2b; b -= 8192; }
  else if (b < 24576) { src = w3; dst = w3b; b -= 16384; }
  else if (b < 26624) { src = wsg; dst = wsgb; b -= 24576; }
  else if (b < 28672) { src = wsu; dst = wsub; b -= 26624; }
  else { src = wsd; dst = wsdb; b -= 28672; }
  size_t off = ((size_t)b * 256 + threadIdx.x) * 8;
  cvt8_nt((const unsigned*)(src + off), dst + off);
}

// ------- kernel 1: router (wave per token) + x->bf16 conversion fused -----
__global__ __launch_bounds__(256) void k_router(const float* __restrict__ x,
                                                const float* __restrict__ gate_w,
                                                const float* __restrict__ sgw,
                                                us* __restrict__ xb,
                                                int* __restrict__ sel,
                                                float* __restrict__ wnorm,
                                                float* __restrict__ sig,
                                                int* __restrict__ counts) {
  __shared__ float lg[4][17];
  int tid = threadIdx.x, wid = tid >> 6, lane = tid & 63;
  int t = blockIdx.x * 4 + wid;
  const float4* xrow = reinterpret_cast<const float4*>(x + (size_t)t * HDIM);
  float4 xv[8];
#pragma unroll
  for (int s = 0; s < 8; s++) xv[s] = xrow[s * 64 + lane];
  ushort4* xbrow = reinterpret_cast<ushort4*>(xb + (size_t)t * HDIM);
#pragma unroll
  for (int s = 0; s < 8; s++) {
    ushort4 o;
    o.x = f2bf(xv[s].x); o.y = f2bf(xv[s].y); o.z = f2bf(xv[s].z); o.w = f2bf(xv[s].w);
    xbrow[s * 64 + lane] = o;
  }
#pragma unroll 2
  for (int e = 0; e < 17; e++) {
    const float4* gr =
        reinterpret_cast<const float4*>(e < 16 ? gate_w + (size_t)e * HDIM : sgw);
    float acc = 0.f;
#pragma unroll
    for (int s = 0; s < 8; s++) {
      float4 g = gr[s * 64 + lane];
      acc += xv[s].x * g.x + xv[s].y * g.y + xv[s].z * g.z + xv[s].w * g.w;
    }
#pragma unroll
    for (int off = 32; off; off >>= 1) acc += __shfl_xor(acc, off, 64);
    if (lane == 0) lg[wid][e] = acc;
  }
  if (lane == 0) {
    float* L = lg[wid];
    int i1 = 0; float v1 = L[0];
    for (int i = 1; i < NEXP; i++) if (L[i] > v1) { v1 = L[i]; i1 = i; }
    int i2 = (i1 == 0) ? 1 : 0; float v2 = L[i2];
    for (int i = 0; i < NEXP; i++)
      if (i != i1 && i != i2 && L[i] > v2) { v2 = L[i]; i2 = i; }
    float wa = 1.f / (1.f + expf(v2 - v1));  // renorm top-2 softmax
    sel[2 * t] = i1; sel[2 * t + 1] = i2;
    wnorm[2 * t] = wa; wnorm[2 * t + 1] = 1.f - wa;
    sig[t] = 1.f / (1.f + expf(-L[16]));
    atomicAdd(&counts[i1], 1);
    atomicAdd(&counts[i2], 1);
  }
}

// ------- kernel 2: per-expert ballot-compaction scatter (16 blocks) -------
// Block e owns expert e: computes its base from a local prefix of counts,
// fills its tile_expert entries, clears its padding rows, and compacts its
// token rows via wave-ballot ranking. No atomics, fully parallel.
__global__ __launch_bounds__(64) void k_scatter(const int* __restrict__ counts,
                                                const int* __restrict__ sel,
                                                const float* __restrict__ wnorm,
                                                int* __restrict__ tile_expert,
                                                int* __restrict__ row_token,
                                                int* __restrict__ rowk,
                                                float* __restrict__ rw) {
  int e = blockIdx.x, lane = threadIdx.x;
  int base = 0, total = 0, nt_e = 0, cnt_e = 0;
  for (int i = 0; i < NEXP; i++) {
    int c = counts[i];
    int nt = (c + 127) >> 7;
    if (i == e) { base = total; cnt_e = c; nt_e = nt; }
    total += nt << 7;
  }
  for (int i = lane; i < nt_e; i += 64) tile_expert[(base >> 7) + i] = e;
  if (e == NEXP - 1)
    for (int m = (total >> 7) + lane; m < MAXT; m += 64) tile_expert[m] = -1;
  for (int r = cnt_e + lane; r < nt_e * 128; r += 64) row_token[base + r] = -1;
  int run = 0;
  for (int t0 = 0; t0 < NTOK; t0 += 64) {
    int t = t0 + lane;
    int s0 = sel[2 * t], s1 = sel[2 * t + 1];
    int k = (s1 == e) ? 1 : 0;
    bool m = (s0 == e) || (s1 == e);
    unsigned long long mask = __ballot(m);
    int rank = __popcll(mask & ((1ull << lane) - 1ull));
    if (m) {
      int row = base + run + rank;
      row_token[row] = t;
      rowk[row] = k;
      rw[row] = wnorm[2 * t + k];
    }
    run += __popcll(mask);
  }
}

// ------- kernel 3: gate/up GEMM, 128x128 tiles, 512 thr, all-bf16 ---------
// waves 0-3: G matrix (2x2 of 64x64), waves 4-7: U. Epilogue joins via LDS.
// A and B both staged via global_load_lds w=16 with pre-swizzled global src.
__global__ __launch_bounds__(512) void k_gu(
    const us* __restrict__ xb, const us* __restrict__ w1b,
    const us* __restrict__ w3b, const us* __restrict__ wsgb,
    const us* __restrict__ wsub, const int* __restrict__ tile_expert,
    const int* __restrict__ row_token, us* __restrict__ hmid,
    us* __restrict__ hs) {
  __shared__ us As[128 * 64];      // 16KB
  __shared__ us Bs[2][128 * 64];   // 32KB (G,U); reused as 128x128 U-buf in epilogue
  __shared__ int toks_s[128];
  int bid = blockIdx.x, tid = threadIdx.x;
  int w = tid >> 6, lane = tid & 63;
  const us *bG, *bU;
  us* outp;
  int mt, n0, ostride;
  if (bid < GU_EXP) {
    mt = bid >> 2; int nt = bid & 3;
    int e = tile_expert[mt];
    if (e < 0) return;
    if (tid < 128) {
      int tk = row_token[mt * 128 + tid];
      toks_s[tid] = tk < 0 ? 0 : tk;
    }
    bG = w1b + ((size_t)e * IDIM + nt * 128) * HDIM;
    bU = w3b + ((size_t)e * IDIM + nt * 128) * HDIM;
    outp = hmid; ostride = IDIM; n0 = nt * 128;
  } else {
    int sb = bid - GU_EXP;
    mt = sb >> 4; int nt = sb & 15;
    if (tid < 128) toks_s[tid] = mt * 128 + tid;
    bG = wsgb + (size_t)(nt * 128) * HDIM;
    bU = wsub + (size_t)(nt * 128) * HDIM;
    outp = hs; ostride = ISDIM; n0 = nt * 128;
  }
  __syncthreads();
  int lr = lane >> 3, lc = lane & 7;
  int swz = (lc ^ lr) * 8;
  const us* aSrc0 = xb + (size_t)toks_s[w * 16 + lr] * HDIM + swz;
  const us* aSrc1 = xb + (size_t)toks_s[w * 16 + 8 + lr] * HDIM + swz;
  int mat = w >> 2, sub = w & 3, wm = sub >> 1, wn = sub & 1;
  // wave (mat,sub) stages B rows [sub*32, sub*32+32) of its own matrix
  const us* bSrc = (mat ? bU : bG) + (size_t)(sub * 32 + lr) * HDIM + swz;
  us* bDst = &Bs[mat][sub * 32 * 64];
  int quad = lane >> 4, l16 = lane & 15, sw = l16 & 7;
  f32x4 acc[4][4] = {};
  for (int k0 = 0; k0 < HDIM; k0 += 64) {
    glds16(aSrc0 + k0, As + w * 1024);
    glds16(aSrc1 + k0, As + w * 1024 + 512);
#pragma unroll
    for (int g = 0; g < 4; g++)
      glds16(bSrc + (size_t)(g * 8) * HDIM + k0, bDst + g * 512);
    __syncthreads();
#pragma unroll
    for (int ks = 0; ks < 2; ks++) {
      int cb = (ks * 4 + quad) ^ sw;
      bf16x8 af[4], bf[4];
#pragma unroll
      for (int ms = 0; ms < 4; ms++)
        af[ms] = *(const bf16x8*)&As[((wm * 64 + ms * 16 + l16) * 8 + cb) * 8];
#pragma unroll
      for (int ns = 0; ns < 4; ns++)
        bf[ns] = *(const bf16x8*)&Bs[mat][((wn * 64 + ns * 16 + l16) * 8 + cb) * 8];
#pragma unroll
      for (int ms = 0; ms < 4; ms++)
#pragma unroll
        for (int ns = 0; ns < 4; ns++)
          acc[ms][ns] = __builtin_amdgcn_mfma_f32_16x16x32_bf16(af[ms], bf[ns], acc[ms][ns], 0, 0, 0);
    }
    __syncthreads();
  }
  // epilogue: U waves park u (bf16) in LDS; G waves do silu(g)*u -> store
  us* ub = (us*)Bs;
  if (mat == 1) {
#pragma unroll
    for (int ms = 0; ms < 4; ms++)
#pragma unroll
      for (int ns = 0; ns < 4; ns++)
#pragma unroll
        for (int r = 0; r < 4; r++) {
          int row = wm * 64 + ms * 16 + quad * 4 + r;
          int col = wn * 64 + ns * 16 + l16;
          ub[row * 128 + col] = f2bf(acc[ms][ns][r]);
        }
  }
  __syncthreads();
  if (mat == 0) {
#pragma unroll
    for (int ms = 0; ms < 4; ms++)
#pragma unroll
      for (int ns = 0; ns < 4; ns++)
#pragma unroll
        for (int r = 0; r < 4; r++) {
          int row = wm * 64 + ms * 16 + quad * 4 + r;
          int col = wn * 64 + ns * 16 + l16;
          float g = acc[ms][ns][r];
          float u = bf2f(ub[row * 128 + col]);
          float hv = (g / (1.f + __expf(-g))) * u;
          outp[(size_t)(mt * 128 + row) * ostride + n0 + col] = f2bf(hv);
        }
  }
}

// ------- kernel 4: down GEMMs 128x256, all-bf16, weighted stores ----------
__global__ __launch_bounds__(512) void k_down(
    const us* __restrict__ hmid, const us* __restrict__ hs,
    const us* __restrict__ w2b, const us* __restrict__ wsdb,
    const int* __restrict__ tile_expert, const int* __restrict__ row_token,
    const int* __restrict__ rowk, const float* __restrict__ rw,
    const float* __restrict__ sig, us* __restrict__ slab) {
  __shared__ us As[128 * 64];   // 16KB
  __shared__ us Bs[256 * 64];   // 32KB
  __shared__ int idx_s[128];
  __shared__ float wgt_s[128];
  int bid = blockIdx.x, tid = threadIdx.x;
  int w = tid >> 6, lane = tid & 63;
  const us* aBase;
  const us* bBase;
  int K, mt, n0;
  if (bid < DN_SH) {  // shared expert first (K=2048, longest)
    mt = bid >> 3; int nt = bid & 7;
    aBase = hs + (size_t)mt * 128 * ISDIM; K = ISDIM;
    bBase = wsdb + (size_t)(nt * 256) * ISDIM;
    n0 = nt * 256;
    if (tid < 128) {
      int t = mt * 128 + tid;
      idx_s[tid] = 2 * NTOK * HDIM + t * HDIM;
      wgt_s[tid] = sig[t];
    }
  } else {
    int sb = bid - DN_SH;
    mt = sb >> 3; int nt = sb & 7;
    int e = tile_expert[mt];
    if (e < 0) return;
    aBase = hmid + (size_t)mt * 128 * IDIM; K = IDIM;
    bBase = w2b + ((size_t)e * HDIM + nt * 256) * IDIM;
    n0 = nt * 256;
    if (tid < 128) {
      int tk = row_token[mt * 128 + tid];
      if (tk < 0) { idx_s[tid] = -1; wgt_s[tid] = 0.f; }
      else {
        idx_s[tid] = (rowk[mt * 128 + tid] * NTOK + tk) * HDIM;
        wgt_s[tid] = rw[mt * 128 + tid];
      }
    }
  }
  __syncthreads();
  int lr = lane >> 3, lc = lane & 7;
  int swz = (lc ^ lr) * 8;
  const us* aSrc0 = aBase + (size_t)(w * 16 + lr) * K + swz;
  const us* aSrc1 = aBase + (size_t)(w * 16 + 8 + lr) * K + swz;
  // wave w stages B rows [w*32, w*32+32)
  const us* bSrc = bBase + (size_t)(w * 32 + lr) * K + swz;
  us* bDst = Bs + w * 32 * 64;
  int wmn = w >> 2, wn = w & 3;  // waves 2(m) x 4(n)
  int quad = lane >> 4, l16 = lane & 15, sw = l16 & 7;
  f32x4 acc[4][4] = {};
  for (int k0 = 0; k0 < K; k0 += 64) {
    glds16(aSrc0 + k0, As + w * 1024);
    glds16(aSrc1 + k0, As + w * 1024 + 512);
#pragma unroll
    for (int g = 0; g < 4; g++)
      glds16(bSrc + (size_t)(g * 8) * K + k0, bDst + g * 512);
    __syncthreads();
#pragma unroll
    for (int ks = 0; ks < 2; ks++) {
      int cb = (ks * 4 + quad) ^ sw;
      bf16x8 af[4], bf[4];
#pragma unroll
      for (int ms = 0; ms < 4; ms++)
        af[ms] = *(const bf16x8*)&As[((wmn * 64 + ms * 16 + l16) * 8 + cb) * 8];
#pragma unroll
      for (int ns = 0; ns < 4; ns++)
        bf[ns] = *(const bf16x8*)&Bs[((wn * 64 + ns * 16 + l16) * 8 + cb) * 8];
#pragma unroll
      for (int ms = 0; ms < 4; ms++)
#pragma unroll
        for (int ns = 0; ns < 4; ns++)
          acc[ms][ns] = __builtin_amdgcn_mfma_f32_16x16x32_bf16(af[ms], bf[ns], acc[ms][ns], 0, 0, 0);
    }
    __syncthreads();
  }
#pragma unroll
  for (int ms = 0; ms < 4; ms++)
#pragma unroll
    for (int r = 0; r < 4; r++) {
      int rr = wmn * 64 + ms * 16 + quad * 4 + r;
      int ix = idx_s[rr];
      if (ix >= 0) {
        float wgt = wgt_s[rr];
        us* orow = slab + (size_t)ix + n0 + wn * 64;
#pragma unroll
        for (int ns = 0; ns < 4; ns++)
          orow[ns * 16 + l16] = f2bf(wgt * acc[ms][ns][r]);
      }
    }
}

// ------- kernel 5: out = slot0 + slot1 + shared (streaming, nt) -----------
__global__ __launch_bounds__(256) void k_combine(const us* __restrict__ slab,
                                                 float* __restrict__ out) {
  size_t i = ((size_t)blockIdx.x * 256 + threadIdx.x) * 8;
  bf16x8 a = __builtin_nontemporal_load((const bf16x8*)(slab + i));
  bf16x8 b = __builtin_nontemporal_load((const bf16x8*)(slab + (size_t)NTOK * HDIM + i));
  bf16x8 c = __builtin_nontemporal_load((const bf16x8*)(slab + 2 * (size_t)NTOK * HDIM + i));
  f32x4 o0, o1;
#pragma unroll
  for (int j = 0; j < 4; j++)
    o0[j] = bf2f((us)a[j]) + bf2f((us)b[j]) + bf2f((us)c[j]);
#pragma unroll
  for (int j = 0; j < 4; j++)
    o1[j] = bf2f((us)a[4 + j]) + bf2f((us)b[4 + j]) + bf2f((us)c[4 + j]);
  __builtin_nontemporal_store(o0, (f32x4*)(out + i));
  __builtin_nontemporal_store(o1, (f32x4*)(out + i + 4));
}

extern "C" void kernel_launch(void* const* d_in, const int* in_sizes, int n_in,
                              void* d_out, int out_size, void* d_ws, size_t ws_size,
                              hipStream_t stream) {
  const float* x = (const float*)d_in[0];
  const float* gate_w = (const float*)d_in[1];
  const float* w1 = (const float*)d_in[2];
  const float* w2 = (const float*)d_in[3];
  const float* w3 = (const float*)d_in[4];
  const float* wsg = (const float*)d_in[5];
  const float* wsu = (const float*)d_in[6];
  const float* wsd = (const float*)d_in[7];
  const float* sgw = (const float*)d_in[8];
  float* out = (float*)d_out;

  // workspace carve (16B aligned)
  us* xb = (us*)d_ws;                               // NTOK*HDIM
  us* hs = xb + (size_t)NTOK * HDIM;                // NTOK*ISDIM
  us* hmid = hs + (size_t)NTOK * ISDIM;             // ROWSCAP*IDIM
  us* slab = hmid + (size_t)ROWSCAP * IDIM;         // 3*NTOK*HDIM
  us* w1b = slab + (size_t)3 * NTOK * HDIM;         // E*I*H
  us* w3b = w1b + (size_t)NEXP * IDIM * HDIM;       // E*I*H
  us* w2b = w3b + (size_t)NEXP * IDIM * HDIM;       // E*H*I
  us* wsgb = w2b + (size_t)NEXP * HDIM * IDIM;      // IS*H
  us* wsub = wsgb + (size_t)ISDIM * HDIM;           // IS*H
  us* wsdb = wsub + (size_t)ISDIM * HDIM;           // H*IS
  float* rw = (float*)(wsdb + (size_t)HDIM * ISDIM);  // ROWSCAP
  float* wnorm = rw + ROWSCAP;                      // 4096
  float* sig = wnorm + 2 * NTOK;                    // 2048
  int* sel = (int*)(sig + NTOK);                    // 4096
  int* row_token = sel + 2 * NTOK;                  // ROWSCAP
  int* rowk = row_token + ROWSCAP;                  // ROWSCAP
  int* counts = rowk + ROWSCAP;                     // 16
  int* tile_expert = counts + NEXP;                 // MAXT

  hipMemsetAsync(counts, 0, NEXP * sizeof(int), stream);
  k_cvt<<<dim3(30720), dim3(256), 0, stream>>>(w1, w2, w3, wsg, wsu, wsd,
                                               w1b, w2b, w3b, wsgb, wsub, wsdb);
  k_router<<<dim3(NTOK / 4), dim3(256), 0, stream>>>(x, gate_w, sgw, xb, sel, wnorm,
                                                     sig, counts);
  k_scatter<<<dim3(NEXP), dim3(64), 0, stream>>>(counts, sel, wnorm, tile_expert,
                                                 row_token, rowk, rw);
  k_gu<<<dim3(GU_EXP + GU_SH), dim3(512), 0, stream>>>(
      xb, w1b, w3b, wsgb, wsub, tile_expert, row_token, hmid, hs);
  k_down<<<dim3(DN_SH + DN_EXP), dim3(512), 0, stream>>>(
      hmid, hs, w2b, wsdb, tile_expert, row_token, rowk, rw, sig, slab);
  k_combine<<<dim3(NTOK * HDIM / 2048), dim3(256), 0, stream>>>(slab, out);
}

// Round 4
// 428.953 us; speedup vs baseline: 1.0872x; 1.0801x over previous
//
#include <hip/hip_runtime.h>
#include <cmath>

#define HDIM 2048
#define NEXP 16
#define IDIM 512
#define ISDIM 2048
#define NTOK 2048
#define MAXT 48                 // 128-row expert tiles: 4096/128 + 16
#define ROWSCAP (MAXT * 128)    // 6144

#define GU_EXP (MAXT * 4)                    // 192 (IDIM/128 = 4 n-tiles)
#define GU_SH ((NTOK / 128) * (ISDIM / 128)) // 256
#define DN_SH ((NTOK / 128) * (HDIM / 256))  // 128
#define DN_EXP (MAXT * 8)                    // 384 (HDIM/256 = 8 n-tiles)

typedef short bf16x8 __attribute__((ext_vector_type(8)));
typedef float f32x4 __attribute__((ext_vector_type(4)));
typedef unsigned int u32x4 __attribute__((ext_vector_type(4)));
typedef unsigned short us;
typedef __attribute__((address_space(1))) const unsigned int* as1p;
typedef __attribute__((address_space(3))) unsigned int* as3p;

__device__ __forceinline__ us f2bf(float f) {
  unsigned int u = __builtin_bit_cast(unsigned int, f);
  u += 0x7FFFu + ((u >> 16) & 1u);
  return (us)(u >> 16);
}
__device__ __forceinline__ float bf2f(us v) {
  return __builtin_bit_cast(float, (unsigned)v << 16);
}

// async 16B/lane global->LDS; global vaddr per-lane, LDS base wave-uniform
__device__ __forceinline__ void glds16(const void* g, void* l) {
  __builtin_amdgcn_global_load_lds((as1p)(unsigned long long)g,
                                   (as3p)(unsigned int)(unsigned long long)l, 16, 0, 0);
}

// load 8 fp32 NON-TEMPORAL (single-use stream; don't evict L3), round-half-up
// to bf16 (same arithmetic as all prior passing rounds), 16B cacheable store.
__device__ __forceinline__ void cvt8_nt(const unsigned* __restrict__ src,
                                        us* __restrict__ dst) {
  u32x4 a = __builtin_nontemporal_load((const u32x4*)src);
  u32x4 b = __builtin_nontemporal_load((const u32x4*)(src + 4));
  unsigned u0 = a.x + 0x8000u;
  unsigned u1 = a.y + 0x8000u;
  unsigned u2 = a.z + 0x8000u;
  unsigned u3 = a.w + 0x8000u;
  unsigned u4 = b.x + 0x8000u;
  unsigned u5 = b.y + 0x8000u;
  unsigned u6 = b.z + 0x8000u;
  unsigned u7 = b.w + 0x8000u;
  int4 v;
  v.x = __builtin_amdgcn_perm(u1, u0, 0x07060302);
  v.y = __builtin_amdgcn_perm(u3, u2, 0x07060302);
  v.z = __builtin_amdgcn_perm(u5, u4, 0x07060302);
  v.w = __builtin_amdgcn_perm(u7, u6, 0x07060302);
  *(int4*)dst = v;
}

// ------- kernel 0: one-shot weight fp32->bf16 convert (streaming) ---------
// 8192 floats per block (4 unrolled cvt8 per thread -> 8 loads in flight).
// ranges: w1 2048, w2 2048, w3 2048, wsg 512, wsu 512, wsd 512 => 7680 blocks
__global__ __launch_bounds__(256) void k_cvt(
    const float* __restrict__ w1, const float* __restrict__ w2,
    const float* __restrict__ w3, const float* __restrict__ wsg,
    const float* __restrict__ wsu, const float* __restrict__ wsd,
    us* __restrict__ w1b, us* __restrict__ w2b, us* __restrict__ w3b,
    us* __restrict__ wsgb, us* __restrict__ wsub, us* __restrict__ wsdb) {
  int b = blockIdx.x;
  const float* src;
  us* dst;
  if (b < 2048) { src = w1; dst = w1b; }
  else if (b < 4096) { src = w2; dst = w2b; b -= 2048; }
  else if (b < 6144) { src = w3; dst = w3b; b -= 4096; }
  else if (b < 6656) { src = wsg; dst = wsgb; b -= 6144; }
  else if (b < 7168) { src = wsu; dst = wsub; b -= 6656; }
  else { src = wsd; dst = wsdb; b -= 7168; }
  size_t base = (size_t)b * 8192;
#pragma unroll
  for (int j = 0; j < 4; j++) {
    size_t off = base + ((size_t)j * 256 + threadIdx.x) * 8;
    cvt8_nt((const unsigned*)(src + off), dst + off);
  }
}

// ------- kernel 1: router (wave per token) + x->bf16 conversion fused -----
// Fully-unrolled 8x17 FMA grid (136 independent loads, scheduler hoists) then
// 17 interleaved butterfly reductions -> latency hidden by ILP, no LDS.
__global__ __launch_bounds__(256) void k_router(const float* __restrict__ x,
                                                const float* __restrict__ gate_w,
                                                const float* __restrict__ sgw,
                                                us* __restrict__ xb,
                                                int* __restrict__ sel,
                                                float* __restrict__ wnorm,
                                                float* __restrict__ sig,
                                                int* __restrict__ counts) {
  int tid = threadIdx.x, wid = tid >> 6, lane = tid & 63;
  int t = blockIdx.x * 4 + wid;
  const float4* xrow = reinterpret_cast<const float4*>(x + (size_t)t * HDIM);
  float4 xv[8];
#pragma unroll
  for (int s = 0; s < 8; s++) xv[s] = xrow[s * 64 + lane];
  ushort4* xbrow = reinterpret_cast<ushort4*>(xb + (size_t)t * HDIM);
#pragma unroll
  for (int s = 0; s < 8; s++) {
    ushort4 o;
    o.x = f2bf(xv[s].x); o.y = f2bf(xv[s].y); o.z = f2bf(xv[s].z); o.w = f2bf(xv[s].w);
    xbrow[s * 64 + lane] = o;
  }
  const float4* gr[17];
#pragma unroll
  for (int e = 0; e < 17; e++)
    gr[e] = reinterpret_cast<const float4*>(e < 16 ? gate_w + (size_t)e * HDIM : sgw);
  float acc[17];
#pragma unroll
  for (int e = 0; e < 17; e++) acc[e] = 0.f;
#pragma unroll
  for (int s = 0; s < 8; s++) {
#pragma unroll
    for (int e = 0; e < 17; e++) {
      float4 g = gr[e][s * 64 + lane];
      acc[e] += xv[s].x * g.x + xv[s].y * g.y + xv[s].z * g.z + xv[s].w * g.w;
    }
  }
#pragma unroll
  for (int off = 32; off; off >>= 1) {
#pragma unroll
    for (int e = 0; e < 17; e++) acc[e] += __shfl_xor(acc[e], off, 64);
  }
  if (lane == 0) {
    int i1 = 0; float v1 = acc[0];
#pragma unroll
    for (int i = 1; i < NEXP; i++) if (acc[i] > v1) { v1 = acc[i]; i1 = i; }
    int i2 = (i1 == 0) ? 1 : 0; float v2 = acc[i2];
#pragma unroll
    for (int i = 0; i < NEXP; i++)
      if (i != i1 && i != i2 && acc[i] > v2) { v2 = acc[i]; i2 = i; }
    float wa = 1.f / (1.f + expf(v2 - v1));  // renorm top-2 softmax
    sel[2 * t] = i1; sel[2 * t + 1] = i2;
    wnorm[2 * t] = wa; wnorm[2 * t + 1] = 1.f - wa;
    sig[t] = 1.f / (1.f + expf(-acc[16]));
    atomicAdd(&counts[i1], 1);
    atomicAdd(&counts[i2], 1);
  }
}

// ------- kernel 2: per-expert ballot-compaction scatter (16 blocks) -------
__global__ __launch_bounds__(64) void k_scatter(const int* __restrict__ counts,
                                                const int* __restrict__ sel,
                                                const float* __restrict__ wnorm,
                                                int* __restrict__ tile_expert,
                                                int* __restrict__ row_token,
                                                int* __restrict__ rowk,
                                                float* __restrict__ rw) {
  int e = blockIdx.x, lane = threadIdx.x;
  int base = 0, total = 0, nt_e = 0, cnt_e = 0;
  for (int i = 0; i < NEXP; i++) {
    int c = counts[i];
    int nt = (c + 127) >> 7;
    if (i == e) { base = total; cnt_e = c; nt_e = nt; }
    total += nt << 7;
  }
  for (int i = lane; i < nt_e; i += 64) tile_expert[(base >> 7) + i] = e;
  if (e == NEXP - 1)
    for (int m = (total >> 7) + lane; m < MAXT; m += 64) tile_expert[m] = -1;
  for (int r = cnt_e + lane; r < nt_e * 128; r += 64) row_token[base + r] = -1;
  int run = 0;
  for (int t0 = 0; t0 < NTOK; t0 += 64) {
    int t = t0 + lane;
    int s0 = sel[2 * t], s1 = sel[2 * t + 1];
    int k = (s1 == e) ? 1 : 0;
    bool m = (s0 == e) || (s1 == e);
    unsigned long long mask = __ballot(m);
    int rank = __popcll(mask & ((1ull << lane) - 1ull));
    if (m) {
      int row = base + run + rank;
      row_token[row] = t;
      rowk[row] = k;
      rw[row] = wnorm[2 * t + k];
    }
    run += __popcll(mask);
  }
}

// ------- kernel 3: gate/up GEMM, 128x128 tiles, 512 thr, all-bf16 ---------
// waves 0-3: G matrix (2x2 of 64x64), waves 4-7: U. Epilogue joins via LDS.
// A and B both staged via global_load_lds w=16 with pre-swizzled global src.
__global__ __launch_bounds__(512) void k_gu(
    const us* __restrict__ xb, const us* __restrict__ w1b,
    const us* __restrict__ w3b, const us* __restrict__ wsgb,
    const us* __restrict__ wsub, const int* __restrict__ tile_expert,
    const int* __restrict__ row_token, us* __restrict__ hmid,
    us* __restrict__ hs) {
  __shared__ us As[128 * 64];      // 16KB
  __shared__ us Bs[2][128 * 64];   // 32KB (G,U); reused as 128x128 U-buf in epilogue
  __shared__ int toks_s[128];
  int bid = blockIdx.x, tid = threadIdx.x;
  int w = tid >> 6, lane = tid & 63;
  const us *bG, *bU;
  us* outp;
  int mt, n0, ostride;
  if (bid < GU_EXP) {
    mt = bid >> 2; int nt = bid & 3;
    int e = tile_expert[mt];
    if (e < 0) return;
    if (tid < 128) {
      int tk = row_token[mt * 128 + tid];
      toks_s[tid] = tk < 0 ? 0 : tk;
    }
    bG = w1b + ((size_t)e * IDIM + nt * 128) * HDIM;
    bU = w3b + ((size_t)e * IDIM + nt * 128) * HDIM;
    outp = hmid; ostride = IDIM; n0 = nt * 128;
  } else {
    int sb = bid - GU_EXP;
    mt = sb >> 4; int nt = sb & 15;
    if (tid < 128) toks_s[tid] = mt * 128 + tid;
    bG = wsgb + (size_t)(nt * 128) * HDIM;
    bU = wsub + (size_t)(nt * 128) * HDIM;
    outp = hs; ostride = ISDIM; n0 = nt * 128;
  }
  __syncthreads();
  int lr = lane >> 3, lc = lane & 7;
  int swz = (lc ^ lr) * 8;
  const us* aSrc0 = xb + (size_t)toks_s[w * 16 + lr] * HDIM + swz;
  const us* aSrc1 = xb + (size_t)toks_s[w * 16 + 8 + lr] * HDIM + swz;
  int mat = w >> 2, sub = w & 3, wm = sub >> 1, wn = sub & 1;
  // wave (mat,sub) stages B rows [sub*32, sub*32+32) of its own matrix
  const us* bSrc = (mat ? bU : bG) + (size_t)(sub * 32 + lr) * HDIM + swz;
  us* bDst = &Bs[mat][sub * 32 * 64];
  int quad = lane >> 4, l16 = lane & 15, sw = l16 & 7;
  f32x4 acc[4][4] = {};
  for (int k0 = 0; k0 < HDIM; k0 += 64) {
    glds16(aSrc0 + k0, As + w * 1024);
    glds16(aSrc1 + k0, As + w * 1024 + 512);
#pragma unroll
    for (int g = 0; g < 4; g++)
      glds16(bSrc + (size_t)(g * 8) * HDIM + k0, bDst + g * 512);
    __syncthreads();
#pragma unroll
    for (int ks = 0; ks < 2; ks++) {
      int cb = (ks * 4 + quad) ^ sw;
      bf16x8 af[4], bf[4];
#pragma unroll
      for (int ms = 0; ms < 4; ms++)
        af[ms] = *(const bf16x8*)&As[((wm * 64 + ms * 16 + l16) * 8 + cb) * 8];
#pragma unroll
      for (int ns = 0; ns < 4; ns++)
        bf[ns] = *(const bf16x8*)&Bs[mat][((wn * 64 + ns * 16 + l16) * 8 + cb) * 8];
#pragma unroll
      for (int ms = 0; ms < 4; ms++)
#pragma unroll
        for (int ns = 0; ns < 4; ns++)
          acc[ms][ns] = __builtin_amdgcn_mfma_f32_16x16x32_bf16(af[ms], bf[ns], acc[ms][ns], 0, 0, 0);
    }
    __syncthreads();
  }
  // epilogue: U waves park u (bf16) in LDS; G waves do silu(g)*u -> store
  us* ub = (us*)Bs;
  if (mat == 1) {
#pragma unroll
    for (int ms = 0; ms < 4; ms++)
#pragma unroll
      for (int ns = 0; ns < 4; ns++)
#pragma unroll
        for (int r = 0; r < 4; r++) {
          int row = wm * 64 + ms * 16 + quad * 4 + r;
          int col = wn * 64 + ns * 16 + l16;
          ub[row * 128 + col] = f2bf(acc[ms][ns][r]);
        }
  }
  __syncthreads();
  if (mat == 0) {
#pragma unroll
    for (int ms = 0; ms < 4; ms++)
#pragma unroll
      for (int ns = 0; ns < 4; ns++)
#pragma unroll
        for (int r = 0; r < 4; r++) {
          int row = wm * 64 + ms * 16 + quad * 4 + r;
          int col = wn * 64 + ns * 16 + l16;
          float g = acc[ms][ns][r];
          float u = bf2f(ub[row * 128 + col]);
          float hv = (g / (1.f + __expf(-g))) * u;
          outp[(size_t)(mt * 128 + row) * ostride + n0 + col] = f2bf(hv);
        }
  }
}

// ------- kernel 4: down GEMMs 128x256, all-bf16, weighted stores ----------
__global__ __launch_bounds__(512) void k_down(
    const us* __restrict__ hmid, const us* __restrict__ hs,
    const us* __restrict__ w2b, const us* __restrict__ wsdb,
    const int* __restrict__ tile_expert, const int* __restrict__ row_token,
    const int* __restrict__ rowk, const float* __restrict__ rw,
    const float* __restrict__ sig, us* __restrict__ slab) {
  __shared__ us As[128 * 64];   // 16KB
  __shared__ us Bs[256 * 64];   // 32KB
  __shared__ int idx_s[128];
  __shared__ float wgt_s[128];
  int bid = blockIdx.x, tid = threadIdx.x;
  int w = tid >> 6, lane = tid & 63;
  const us* aBase;
  const us* bBase;
  int K, mt, n0;
  if (bid < DN_SH) {  // shared expert first (K=2048, longest)
    mt = bid >> 3; int nt = bid & 7;
    aBase = hs + (size_t)mt * 128 * ISDIM; K = ISDIM;
    bBase = wsdb + (size_t)(nt * 256) * ISDIM;
    n0 = nt * 256;
    if (tid < 128) {
      int t = mt * 128 + tid;
      idx_s[tid] = 2 * NTOK * HDIM + t * HDIM;
      wgt_s[tid] = sig[t];
    }
  } else {
    int sb = bid - DN_SH;
    mt = sb >> 3; int nt = sb & 7;
    int e = tile_expert[mt];
    if (e < 0) return;
    aBase = hmid + (size_t)mt * 128 * IDIM; K = IDIM;
    bBase = w2b + ((size_t)e * HDIM + nt * 256) * IDIM;
    n0 = nt * 256;
    if (tid < 128) {
      int tk = row_token[mt * 128 + tid];
      if (tk < 0) { idx_s[tid] = -1; wgt_s[tid] = 0.f; }
      else {
        idx_s[tid] = (rowk[mt * 128 + tid] * NTOK + tk) * HDIM;
        wgt_s[tid] = rw[mt * 128 + tid];
      }
    }
  }
  __syncthreads();
  int lr = lane >> 3, lc = lane & 7;
  int swz = (lc ^ lr) * 8;
  const us* aSrc0 = aBase + (size_t)(w * 16 + lr) * K + swz;
  const us* aSrc1 = aBase + (size_t)(w * 16 + 8 + lr) * K + swz;
  // wave w stages B rows [w*32, w*32+32)
  const us* bSrc = bBase + (size_t)(w * 32 + lr) * K + swz;
  us* bDst = Bs + w * 32 * 64;
  int wmn = w >> 2, wn = w & 3;  // waves 2(m) x 4(n)
  int quad = lane >> 4, l16 = lane & 15, sw = l16 & 7;
  f32x4 acc[4][4] = {};
  for (int k0 = 0; k0 < K; k0 += 64) {
    glds16(aSrc0 + k0, As + w * 1024);
    glds16(aSrc1 + k0, As + w * 1024 + 512);
#pragma unroll
    for (int g = 0; g < 4; g++)
      glds16(bSrc + (size_t)(g * 8) * K + k0, bDst + g * 512);
    __syncthreads();
#pragma unroll
    for (int ks = 0; ks < 2; ks++) {
      int cb = (ks * 4 + quad) ^ sw;
      bf16x8 af[4], bf[4];
#pragma unroll
      for (int ms = 0; ms < 4; ms++)
        af[ms] = *(const bf16x8*)&As[((wmn * 64 + ms * 16 + l16) * 8 + cb) * 8];
#pragma unroll
      for (int ns = 0; ns < 4; ns++)
        bf[ns] = *(const bf16x8*)&Bs[((wn * 64 + ns * 16 + l16) * 8 + cb) * 8];
#pragma unroll
      for (int ms = 0; ms < 4; ms++)
#pragma unroll
        for (int ns = 0; ns < 4; ns++)
          acc[ms][ns] = __builtin_amdgcn_mfma_f32_16x16x32_bf16(af[ms], bf[ns], acc[ms][ns], 0, 0, 0);
    }
    __syncthreads();
  }
#pragma unroll
  for (int ms = 0; ms < 4; ms++)
#pragma unroll
    for (int r = 0; r < 4; r++) {
      int rr = wmn * 64 + ms * 16 + quad * 4 + r;
      int ix = idx_s[rr];
      if (ix >= 0) {
        float wgt = wgt_s[rr];
        us* orow = slab + (size_t)ix + n0 + wn * 64;
#pragma unroll
        for (int ns = 0; ns < 4; ns++)
          orow[ns * 16 + l16] = f2bf(wgt * acc[ms][ns][r]);
      }
    }
}

// ------- kernel 5: out = slot0 + slot1 + shared (streaming, nt) -----------
__global__ __launch_bounds__(256) void k_combine(const us* __restrict__ slab,
                                                 float* __restrict__ out) {
  size_t i = ((size_t)blockIdx.x * 256 + threadIdx.x) * 8;
  bf16x8 a = __builtin_nontemporal_load((const bf16x8*)(slab + i));
  bf16x8 b = __builtin_nontemporal_load((const bf16x8*)(slab + (size_t)NTOK * HDIM + i));
  bf16x8 c = __builtin_nontemporal_load((const bf16x8*)(slab + 2 * (size_t)NTOK * HDIM + i));
  f32x4 o0, o1;
#pragma unroll
  for (int j = 0; j < 4; j++)
    o0[j] = bf2f((us)a[j]) + bf2f((us)b[j]) + bf2f((us)c[j]);
#pragma unroll
  for (int j = 0; j < 4; j++)
    o1[j] = bf2f((us)a[4 + j]) + bf2f((us)b[4 + j]) + bf2f((us)c[4 + j]);
  __builtin_nontemporal_store(o0, (f32x4*)(out + i));
  __builtin_nontemporal_store(o1, (f32x4*)(out + i + 4));
}

extern "C" void kernel_launch(void* const* d_in, const int* in_sizes, int n_in,
                              void* d_out, int out_size, void* d_ws, size_t ws_size,
                              hipStream_t stream) {
  const float* x = (const float*)d_in[0];
  const float* gate_w = (const float*)d_in[1];
  const float* w1 = (const float*)d_in[2];
  const float* w2 = (const float*)d_in[3];
  const float* w3 = (const float*)d_in[4];
  const float* wsg = (const float*)d_in[5];
  const float* wsu = (const float*)d_in[6];
  const float* wsd = (const float*)d_in[7];
  const float* sgw = (const float*)d_in[8];
  float* out = (float*)d_out;

  // workspace carve (16B aligned)
  us* xb = (us*)d_ws;                               // NTOK*HDIM
  us* hs = xb + (size_t)NTOK * HDIM;                // NTOK*ISDIM
  us* hmid = hs + (size_t)NTOK * ISDIM;             // ROWSCAP*IDIM
  us* slab = hmid + (size_t)ROWSCAP * IDIM;         // 3*NTOK*HDIM
  us* w1b = slab + (size_t)3 * NTOK * HDIM;         // E*I*H
  us* w3b = w1b + (size_t)NEXP * IDIM * HDIM;       // E*I*H
  us* w2b = w3b + (size_t)NEXP * IDIM * HDIM;       // E*H*I
  us* wsgb = w2b + (size_t)NEXP * HDIM * IDIM;      // IS*H
  us* wsub = wsgb + (size_t)ISDIM * HDIM;           // IS*H
  us* wsdb = wsub + (size_t)ISDIM * HDIM;           // H*IS
  float* rw = (float*)(wsdb + (size_t)HDIM * ISDIM);  // ROWSCAP
  float* wnorm = rw + ROWSCAP;                      // 4096
  float* sig = wnorm + 2 * NTOK;                    // 2048
  int* sel = (int*)(sig + NTOK);                    // 4096
  int* row_token = sel + 2 * NTOK;                  // ROWSCAP
  int* rowk = row_token + ROWSCAP;                  // ROWSCAP
  int* counts = rowk + ROWSCAP;                     // 16
  int* tile_expert = counts + NEXP;                 // MAXT

  hipMemsetAsync(counts, 0, NEXP * sizeof(int), stream);
  k_cvt<<<dim3(7680), dim3(256), 0, stream>>>(w1, w2, w3, wsg, wsu, wsd,
                                              w1b, w2b, w3b, wsgb, wsub, wsdb);
  k_router<<<dim3(NTOK / 4), dim3(256), 0, stream>>>(x, gate_w, sgw, xb, sel, wnorm,
                                                     sig, counts);
  k_scatter<<<dim3(NEXP), dim3(64), 0, stream>>>(counts, sel, wnorm, tile_expert,
                                                 row_token, rowk, rw);
  k_gu<<<dim3(GU_EXP + GU_SH), dim3(512), 0, stream>>>(
      xb, w1b, w3b, wsgb, wsub, tile_expert, row_token, hmid, hs);
  k_down<<<dim3(DN_SH + DN_EXP), dim3(512), 0, stream>>>(
      hmid, hs, w2b, wsdb, tile_expert, row_token, rowk, rw, sig, slab);
  k_combine<<<dim3(NTOK * HDIM / 2048), dim3(256), 0, stream>>>(slab, out);
}

// Round 5
// 419.118 us; speedup vs baseline: 1.1128x; 1.0235x over previous
//
#include <hip/hip_runtime.h>
#include <cmath>

#define HDIM 2048
#define NEXP 16
#define IDIM 512
#define ISDIM 2048
#define NTOK 2048
#define MAXT 48                 // 128-row expert tiles: 4096/128 + 16
#define ROWSCAP (MAXT * 128)    // 6144

#define GU_EXP (MAXT * 4)                    // 192 (IDIM/128 = 4 n-tiles)
#define GU_SH ((NTOK / 128) * (ISDIM / 128)) // 256
#define DN_SH ((NTOK / 128) * (HDIM / 256))  // 128
#define DN_EXP (MAXT * 8)                    // 384 (HDIM/256 = 8 n-tiles)

typedef short bf16x8 __attribute__((ext_vector_type(8)));
typedef float f32x4 __attribute__((ext_vector_type(4)));
typedef unsigned int u32x4 __attribute__((ext_vector_type(4)));
typedef unsigned short us;
typedef __attribute__((address_space(1))) const unsigned int* as1p;
typedef __attribute__((address_space(3))) unsigned int* as3p;

__device__ __forceinline__ us f2bf(float f) {
  unsigned int u = __builtin_bit_cast(unsigned int, f);
  u += 0x7FFFu + ((u >> 16) & 1u);
  return (us)(u >> 16);
}
__device__ __forceinline__ float bf2f(us v) {
  return __builtin_bit_cast(float, (unsigned)v << 16);
}

// async 16B/lane global->LDS; global vaddr per-lane, LDS base wave-uniform
__device__ __forceinline__ void glds16(const void* g, void* l) {
  __builtin_amdgcn_global_load_lds((as1p)(unsigned long long)g,
                                   (as3p)(unsigned int)(unsigned long long)l, 16, 0, 0);
}

// load 8 fp32 NON-TEMPORAL (single-use stream; don't evict L3), round-half-up
// to bf16 (same arithmetic as all prior passing rounds), 16B cacheable store.
__device__ __forceinline__ void cvt8_nt(const unsigned* __restrict__ src,
                                        us* __restrict__ dst) {
  u32x4 a = __builtin_nontemporal_load((const u32x4*)src);
  u32x4 b = __builtin_nontemporal_load((const u32x4*)(src + 4));
  unsigned u0 = a.x + 0x8000u;
  unsigned u1 = a.y + 0x8000u;
  unsigned u2 = a.z + 0x8000u;
  unsigned u3 = a.w + 0x8000u;
  unsigned u4 = b.x + 0x8000u;
  unsigned u5 = b.y + 0x8000u;
  unsigned u6 = b.z + 0x8000u;
  unsigned u7 = b.w + 0x8000u;
  int4 v;
  v.x = __builtin_amdgcn_perm(u1, u0, 0x07060302);
  v.y = __builtin_amdgcn_perm(u3, u2, 0x07060302);
  v.z = __builtin_amdgcn_perm(u5, u4, 0x07060302);
  v.w = __builtin_amdgcn_perm(u7, u6, 0x07060302);
  *(int4*)dst = v;
}

// ------- kernel 0: one-shot weight fp32->bf16 convert (streaming) ---------
// 16384 floats per block (8 unrolled cvt8 per thread -> 16 loads in flight).
// ranges: w1 1024, w2 1024, w3 1024, wsg 256, wsu 256, wsd 256 => 3840 blocks
__global__ __launch_bounds__(256) void k_cvt(
    const float* __restrict__ w1, const float* __restrict__ w2,
    const float* __restrict__ w3, const float* __restrict__ wsg,
    const float* __restrict__ wsu, const float* __restrict__ wsd,
    us* __restrict__ w1b, us* __restrict__ w2b, us* __restrict__ w3b,
    us* __restrict__ wsgb, us* __restrict__ wsub, us* __restrict__ wsdb) {
  int b = blockIdx.x;
  const float* src;
  us* dst;
  if (b < 1024) { src = w1; dst = w1b; }
  else if (b < 2048) { src = w2; dst = w2b; b -= 1024; }
  else if (b < 3072) { src = w3; dst = w3b; b -= 2048; }
  else if (b < 3328) { src = wsg; dst = wsgb; b -= 3072; }
  else if (b < 3584) { src = wsu; dst = wsub; b -= 3328; }
  else { src = wsd; dst = wsdb; b -= 3584; }
  size_t base = (size_t)b * 16384;
#pragma unroll
  for (int j = 0; j < 8; j++) {
    size_t off = base + ((size_t)j * 256 + threadIdx.x) * 8;
    cvt8_nt((const unsigned*)(src + off), dst + off);
  }
}

// ------- kernel 1: router, 4 waves per token + x->bf16 fused --------------
// Block = one token; wave wid owns H-slice [wid*512,(wid+1)*512). Per wave:
// 2 x-loads + 34 gate loads (L2-hot), 17 interleaved acc chains, butterfly,
// LDS[4][17] cross-wave reduce, thread-0 top-2. 8192 waves total -> 32/CU.
__global__ __launch_bounds__(256) void k_router(const float* __restrict__ x,
                                                const float* __restrict__ gate_w,
                                                const float* __restrict__ sgw,
                                                us* __restrict__ xb,
                                                int* __restrict__ sel,
                                                float* __restrict__ wnorm,
                                                float* __restrict__ sig,
                                                int* __restrict__ counts) {
  __shared__ float lg[4][17];
  __shared__ float L[17];
  int tid = threadIdx.x, wid = tid >> 6, lane = tid & 63;
  int t = blockIdx.x;
  const float4* xrow = reinterpret_cast<const float4*>(x + (size_t)t * HDIM);
  int i0 = wid * 128 + lane;
  float4 xv0 = xrow[i0], xv1 = xrow[i0 + 64];
  ushort4* xbrow = reinterpret_cast<ushort4*>(xb + (size_t)t * HDIM);
  ushort4 o0, o1;
  o0.x = f2bf(xv0.x); o0.y = f2bf(xv0.y); o0.z = f2bf(xv0.z); o0.w = f2bf(xv0.w);
  o1.x = f2bf(xv1.x); o1.y = f2bf(xv1.y); o1.z = f2bf(xv1.z); o1.w = f2bf(xv1.w);
  xbrow[i0] = o0;
  xbrow[i0 + 64] = o1;
  float acc[17];
#pragma unroll
  for (int e = 0; e < 17; e++) acc[e] = 0.f;
#pragma unroll
  for (int e = 0; e < 17; e++) {
    const float4* gr =
        reinterpret_cast<const float4*>(e < 16 ? gate_w + (size_t)e * HDIM : sgw);
    float4 g0 = gr[i0], g1 = gr[i0 + 64];
    acc[e] += xv0.x * g0.x + xv0.y * g0.y + xv0.z * g0.z + xv0.w * g0.w +
              xv1.x * g1.x + xv1.y * g1.y + xv1.z * g1.z + xv1.w * g1.w;
  }
#pragma unroll
  for (int off = 32; off; off >>= 1) {
#pragma unroll
    for (int e = 0; e < 17; e++) acc[e] += __shfl_xor(acc[e], off, 64);
  }
  if (lane == 0) {
#pragma unroll
    for (int e = 0; e < 17; e++) lg[wid][e] = acc[e];
  }
  __syncthreads();
  if (tid < 17) L[tid] = lg[0][tid] + lg[1][tid] + lg[2][tid] + lg[3][tid];
  __syncthreads();
  if (tid == 0) {
    int i1 = 0; float v1 = L[0];
#pragma unroll
    for (int i = 1; i < NEXP; i++) if (L[i] > v1) { v1 = L[i]; i1 = i; }
    int i2 = (i1 == 0) ? 1 : 0; float v2 = L[i2];
#pragma unroll
    for (int i = 0; i < NEXP; i++)
      if (i != i1 && i != i2 && L[i] > v2) { v2 = L[i]; i2 = i; }
    float wa = 1.f / (1.f + expf(v2 - v1));  // renorm top-2 softmax
    sel[2 * t] = i1; sel[2 * t + 1] = i2;
    wnorm[2 * t] = wa; wnorm[2 * t + 1] = 1.f - wa;
    sig[t] = 1.f / (1.f + expf(-L[16]));
    atomicAdd(&counts[i1], 1);
    atomicAdd(&counts[i2], 1);
  }
}

// ------- kernel 2: per-expert ballot-compaction scatter (16 blocks) -------
__global__ __launch_bounds__(64) void k_scatter(const int* __restrict__ counts,
                                                const int* __restrict__ sel,
                                                const float* __restrict__ wnorm,
                                                int* __restrict__ tile_expert,
                                                int* __restrict__ row_token,
                                                int* __restrict__ rowk,
                                                float* __restrict__ rw) {
  int e = blockIdx.x, lane = threadIdx.x;
  int base = 0, total = 0, nt_e = 0, cnt_e = 0;
  for (int i = 0; i < NEXP; i++) {
    int c = counts[i];
    int nt = (c + 127) >> 7;
    if (i == e) { base = total; cnt_e = c; nt_e = nt; }
    total += nt << 7;
  }
  for (int i = lane; i < nt_e; i += 64) tile_expert[(base >> 7) + i] = e;
  if (e == NEXP - 1)
    for (int m = (total >> 7) + lane; m < MAXT; m += 64) tile_expert[m] = -1;
  for (int r = cnt_e + lane; r < nt_e * 128; r += 64) row_token[base + r] = -1;
  int run = 0;
  for (int t0 = 0; t0 < NTOK; t0 += 64) {
    int t = t0 + lane;
    int s0 = sel[2 * t], s1 = sel[2 * t + 1];
    int k = (s1 == e) ? 1 : 0;
    bool m = (s0 == e) || (s1 == e);
    unsigned long long mask = __ballot(m);
    int rank = __popcll(mask & ((1ull << lane) - 1ull));
    if (m) {
      int row = base + run + rank;
      row_token[row] = t;
      rowk[row] = k;
      rw[row] = wnorm[2 * t + k];
    }
    run += __popcll(mask);
  }
}

// ------- kernel 3: gate/up GEMM, 128x128 tiles, 512 thr, all-bf16 ---------
// waves 0-3: G matrix (2x2 of 64x64), waves 4-7: U. Epilogue joins via LDS.
// A and B both staged via global_load_lds w=16 with pre-swizzled global src.
__global__ __launch_bounds__(512) void k_gu(
    const us* __restrict__ xb, const us* __restrict__ w1b,
    const us* __restrict__ w3b, const us* __restrict__ wsgb,
    const us* __restrict__ wsub, const int* __restrict__ tile_expert,
    const int* __restrict__ row_token, us* __restrict__ hmid,
    us* __restrict__ hs) {
  __shared__ us As[128 * 64];      // 16KB
  __shared__ us Bs[2][128 * 64];   // 32KB (G,U); reused as 128x128 U-buf in epilogue
  __shared__ int toks_s[128];
  int bid = blockIdx.x, tid = threadIdx.x;
  int w = tid >> 6, lane = tid & 63;
  const us *bG, *bU;
  us* outp;
  int mt, n0, ostride;
  if (bid < GU_EXP) {
    mt = bid >> 2; int nt = bid & 3;
    int e = tile_expert[mt];
    if (e < 0) return;
    if (tid < 128) {
      int tk = row_token[mt * 128 + tid];
      toks_s[tid] = tk < 0 ? 0 : tk;
    }
    bG = w1b + ((size_t)e * IDIM + nt * 128) * HDIM;
    bU = w3b + ((size_t)e * IDIM + nt * 128) * HDIM;
    outp = hmid; ostride = IDIM; n0 = nt * 128;
  } else {
    int sb = bid - GU_EXP;
    mt = sb >> 4; int nt = sb & 15;
    if (tid < 128) toks_s[tid] = mt * 128 + tid;
    bG = wsgb + (size_t)(nt * 128) * HDIM;
    bU = wsub + (size_t)(nt * 128) * HDIM;
    outp = hs; ostride = ISDIM; n0 = nt * 128;
  }
  __syncthreads();
  int lr = lane >> 3, lc = lane & 7;
  int swz = (lc ^ lr) * 8;
  const us* aSrc0 = xb + (size_t)toks_s[w * 16 + lr] * HDIM + swz;
  const us* aSrc1 = xb + (size_t)toks_s[w * 16 + 8 + lr] * HDIM + swz;
  int mat = w >> 2, sub = w & 3, wm = sub >> 1, wn = sub & 1;
  // wave (mat,sub) stages B rows [sub*32, sub*32+32) of its own matrix
  const us* bSrc = (mat ? bU : bG) + (size_t)(sub * 32 + lr) * HDIM + swz;
  us* bDst = &Bs[mat][sub * 32 * 64];
  int quad = lane >> 4, l16 = lane & 15, sw = l16 & 7;
  f32x4 acc[4][4] = {};
  for (int k0 = 0; k0 < HDIM; k0 += 64) {
    glds16(aSrc0 + k0, As + w * 1024);
    glds16(aSrc1 + k0, As + w * 1024 + 512);
#pragma unroll
    for (int g = 0; g < 4; g++)
      glds16(bSrc + (size_t)(g * 8) * HDIM + k0, bDst + g * 512);
    __syncthreads();
#pragma unroll
    for (int ks = 0; ks < 2; ks++) {
      int cb = (ks * 4 + quad) ^ sw;
      bf16x8 af[4], bf[4];
#pragma unroll
      for (int ms = 0; ms < 4; ms++)
        af[ms] = *(const bf16x8*)&As[((wm * 64 + ms * 16 + l16) * 8 + cb) * 8];
#pragma unroll
      for (int ns = 0; ns < 4; ns++)
        bf[ns] = *(const bf16x8*)&Bs[mat][((wn * 64 + ns * 16 + l16) * 8 + cb) * 8];
#pragma unroll
      for (int ms = 0; ms < 4; ms++)
#pragma unroll
        for (int ns = 0; ns < 4; ns++)
          acc[ms][ns] = __builtin_amdgcn_mfma_f32_16x16x32_bf16(af[ms], bf[ns], acc[ms][ns], 0, 0, 0);
    }
    __syncthreads();
  }
  // epilogue: U waves park u (bf16) in LDS; G waves do silu(g)*u -> store
  us* ub = (us*)Bs;
  if (mat == 1) {
#pragma unroll
    for (int ms = 0; ms < 4; ms++)
#pragma unroll
      for (int ns = 0; ns < 4; ns++)
#pragma unroll
        for (int r = 0; r < 4; r++) {
          int row = wm * 64 + ms * 16 + quad * 4 + r;
          int col = wn * 64 + ns * 16 + l16;
          ub[row * 128 + col] = f2bf(acc[ms][ns][r]);
        }
  }
  __syncthreads();
  if (mat == 0) {
#pragma unroll
    for (int ms = 0; ms < 4; ms++)
#pragma unroll
      for (int ns = 0; ns < 4; ns++)
#pragma unroll
        for (int r = 0; r < 4; r++) {
          int row = wm * 64 + ms * 16 + quad * 4 + r;
          int col = wn * 64 + ns * 16 + l16;
          float g = acc[ms][ns][r];
          float u = bf2f(ub[row * 128 + col]);
          float hv = (g / (1.f + __expf(-g))) * u;
          outp[(size_t)(mt * 128 + row) * ostride + n0 + col] = f2bf(hv);
        }
  }
}

// ------- kernel 4: down GEMMs 128x256, all-bf16, weighted stores ----------
__global__ __launch_bounds__(512) void k_down(
    const us* __restrict__ hmid, const us* __restrict__ hs,
    const us* __restrict__ w2b, const us* __restrict__ wsdb,
    const int* __restrict__ tile_expert, const int* __restrict__ row_token,
    const int* __restrict__ rowk, const float* __restrict__ rw,
    const float* __restrict__ sig, us* __restrict__ slab) {
  __shared__ us As[128 * 64];   // 16KB
  __shared__ us Bs[256 * 64];   // 32KB
  __shared__ int idx_s[128];
  __shared__ float wgt_s[128];
  int bid = blockIdx.x, tid = threadIdx.x;
  int w = tid >> 6, lane = tid & 63;
  const us* aBase;
  const us* bBase;
  int K, mt, n0;
  if (bid < DN_SH) {  // shared expert first (K=2048, longest)
    mt = bid >> 3; int nt = bid & 7;
    aBase = hs + (size_t)mt * 128 * ISDIM; K = ISDIM;
    bBase = wsdb + (size_t)(nt * 256) * ISDIM;
    n0 = nt * 256;
    if (tid < 128) {
      int t = mt * 128 + tid;
      idx_s[tid] = 2 * NTOK * HDIM + t * HDIM;
      wgt_s[tid] = sig[t];
    }
  } else {
    int sb = bid - DN_SH;
    mt = sb >> 3; int nt = sb & 7;
    int e = tile_expert[mt];
    if (e < 0) return;
    aBase = hmid + (size_t)mt * 128 * IDIM; K = IDIM;
    bBase = w2b + ((size_t)e * HDIM + nt * 256) * IDIM;
    n0 = nt * 256;
    if (tid < 128) {
      int tk = row_token[mt * 128 + tid];
      if (tk < 0) { idx_s[tid] = -1; wgt_s[tid] = 0.f; }
      else {
        idx_s[tid] = (rowk[mt * 128 + tid] * NTOK + tk) * HDIM;
        wgt_s[tid] = rw[mt * 128 + tid];
      }
    }
  }
  __syncthreads();
  int lr = lane >> 3, lc = lane & 7;
  int swz = (lc ^ lr) * 8;
  const us* aSrc0 = aBase + (size_t)(w * 16 + lr) * K + swz;
  const us* aSrc1 = aBase + (size_t)(w * 16 + 8 + lr) * K + swz;
  // wave w stages B rows [w*32, w*32+32)
  const us* bSrc = bBase + (size_t)(w * 32 + lr) * K + swz;
  us* bDst = Bs + w * 32 * 64;
  int wmn = w >> 2, wn = w & 3;  // waves 2(m) x 4(n)
  int quad = lane >> 4, l16 = lane & 15, sw = l16 & 7;
  f32x4 acc[4][4] = {};
  for (int k0 = 0; k0 < K; k0 += 64) {
    glds16(aSrc0 + k0, As + w * 1024);
    glds16(aSrc1 + k0, As + w * 1024 + 512);
#pragma unroll
    for (int g = 0; g < 4; g++)
      glds16(bSrc + (size_t)(g * 8) * K + k0, bDst + g * 512);
    __syncthreads();
#pragma unroll
    for (int ks = 0; ks < 2; ks++) {
      int cb = (ks * 4 + quad) ^ sw;
      bf16x8 af[4], bf[4];
#pragma unroll
      for (int ms = 0; ms < 4; ms++)
        af[ms] = *(const bf16x8*)&As[((wmn * 64 + ms * 16 + l16) * 8 + cb) * 8];
#pragma unroll
      for (int ns = 0; ns < 4; ns++)
        bf[ns] = *(const bf16x8*)&Bs[((wn * 64 + ns * 16 + l16) * 8 + cb) * 8];
#pragma unroll
      for (int ms = 0; ms < 4; ms++)
#pragma unroll
        for (int ns = 0; ns < 4; ns++)
          acc[ms][ns] = __builtin_amdgcn_mfma_f32_16x16x32_bf16(af[ms], bf[ns], acc[ms][ns], 0, 0, 0);
    }
    __syncthreads();
  }
#pragma unroll
  for (int ms = 0; ms < 4; ms++)
#pragma unroll
    for (int r = 0; r < 4; r++) {
      int rr = wmn * 64 + ms * 16 + quad * 4 + r;
      int ix = idx_s[rr];
      if (ix >= 0) {
        float wgt = wgt_s[rr];
        us* orow = slab + (size_t)ix + n0 + wn * 64;
#pragma unroll
        for (int ns = 0; ns < 4; ns++)
          orow[ns * 16 + l16] = f2bf(wgt * acc[ms][ns][r]);
      }
    }
}

// ------- kernel 5: out = slot0 + slot1 + shared (streaming, nt) -----------
__global__ __launch_bounds__(256) void k_combine(const us* __restrict__ slab,
                                                 float* __restrict__ out) {
  size_t i = ((size_t)blockIdx.x * 256 + threadIdx.x) * 8;
  bf16x8 a = __builtin_nontemporal_load((const bf16x8*)(slab + i));
  bf16x8 b = __builtin_nontemporal_load((const bf16x8*)(slab + (size_t)NTOK * HDIM + i));
  bf16x8 c = __builtin_nontemporal_load((const bf16x8*)(slab + 2 * (size_t)NTOK * HDIM + i));
  f32x4 o0, o1;
#pragma unroll
  for (int j = 0; j < 4; j++)
    o0[j] = bf2f((us)a[j]) + bf2f((us)b[j]) + bf2f((us)c[j]);
#pragma unroll
  for (int j = 0; j < 4; j++)
    o1[j] = bf2f((us)a[4 + j]) + bf2f((us)b[4 + j]) + bf2f((us)c[4 + j]);
  __builtin_nontemporal_store(o0, (f32x4*)(out + i));
  __builtin_nontemporal_store(o1, (f32x4*)(out + i + 4));
}

extern "C" void kernel_launch(void* const* d_in, const int* in_sizes, int n_in,
                              void* d_out, int out_size, void* d_ws, size_t ws_size,
                              hipStream_t stream) {
  const float* x = (const float*)d_in[0];
  const float* gate_w = (const float*)d_in[1];
  const float* w1 = (const float*)d_in[2];
  const float* w2 = (const float*)d_in[3];
  const float* w3 = (const float*)d_in[4];
  const float* wsg = (const float*)d_in[5];
  const float* wsu = (const float*)d_in[6];
  const float* wsd = (const float*)d_in[7];
  const float* sgw = (const float*)d_in[8];
  float* out = (float*)d_out;

  // workspace carve (16B aligned)
  us* xb = (us*)d_ws;                               // NTOK*HDIM
  us* hs = xb + (size_t)NTOK * HDIM;                // NTOK*ISDIM
  us* hmid = hs + (size_t)NTOK * ISDIM;             // ROWSCAP*IDIM
  us* slab = hmid + (size_t)ROWSCAP * IDIM;         // 3*NTOK*HDIM
  us* w1b = slab + (size_t)3 * NTOK * HDIM;         // E*I*H
  us* w3b = w1b + (size_t)NEXP * IDIM * HDIM;       // E*I*H
  us* w2b = w3b + (size_t)NEXP * IDIM * HDIM;       // E*H*I
  us* wsgb = w2b + (size_t)NEXP * HDIM * IDIM;      // IS*H
  us* wsub = wsgb + (size_t)ISDIM * HDIM;           // IS*H
  us* wsdb = wsub + (size_t)ISDIM * HDIM;           // H*IS
  float* rw = (float*)(wsdb + (size_t)HDIM * ISDIM);  // ROWSCAP
  float* wnorm = rw + ROWSCAP;                      // 4096
  float* sig = wnorm + 2 * NTOK;                    // 2048
  int* sel = (int*)(sig + NTOK);                    // 4096
  int* row_token = sel + 2 * NTOK;                  // ROWSCAP
  int* rowk = row_token + ROWSCAP;                  // ROWSCAP
  int* counts = rowk + ROWSCAP;                     // 16
  int* tile_expert = counts + NEXP;                 // MAXT

  hipMemsetAsync(counts, 0, NEXP * sizeof(int), stream);
  k_cvt<<<dim3(3840), dim3(256), 0, stream>>>(w1, w2, w3, wsg, wsu, wsd,
                                              w1b, w2b, w3b, wsgb, wsub, wsdb);
  k_router<<<dim3(NTOK), dim3(256), 0, stream>>>(x, gate_w, sgw, xb, sel, wnorm,
                                                 sig, counts);
  k_scatter<<<dim3(NEXP), dim3(64), 0, stream>>>(counts, sel, wnorm, tile_expert,
                                                 row_token, rowk, rw);
  k_gu<<<dim3(GU_EXP + GU_SH), dim3(512), 0, stream>>>(
      xb, w1b, w3b, wsgb, wsub, tile_expert, row_token, hmid, hs);
  k_down<<<dim3(DN_SH + DN_EXP), dim3(512), 0, stream>>>(
      hmid, hs, w2b, wsdb, tile_expert, row_token, rowk, rw, sig, slab);
  k_combine<<<dim3(NTOK * HDIM / 2048), dim3(256), 0, stream>>>(slab, out);
}